// Round 15
// baseline (487.153 us; speedup 1.0000x reference)
//
#include <hip/hip_runtime.h>
#include <hip/hip_fp16.h>

// ---------------------------------------------------------------------------
// LinkPredictionGNN: 2x GCNConv (self-loops, sym-norm) + pair MLP head.
//   memset gcnt/gcur -> K1 prep_w UNION hist -> K2 multisplit -> K3 bucket
//   K4 gemm1 (fp32 x, bf16-split, rowscale=dinv) -> K5..K8 agg1 x4 slices
//   K9 gemm2_f16 -> K10..K13 agg2 x4 slices -> K14 gemm_dual_f16 -> K15 pairs
//
// R1/R4: random 4B global writes/atomics -> ~10x line-writeback amp; spatial
//   XCD-affinity tricks regress. R6/R7: column-sliced gather in ONE dispatch
//   fails (phases overlap; XCD L2 locality not schedulable intra-dispatch).
// R5: CSR build = 2-level bucket sort, zero global random atomics.
// R8: fp32 gemm X-tile staged via coalesced float2->LDS.
// R12 FAILED: per-edge dinv[src] in agg broke pipelining; R13 reverted
//   normalization to gemm1 epilogue, kept fp16 h1/h2 + f16 2-MFMA GEMMs.
// R14: agg sliced BY DISPATCH: 4 sequential launches per conv, slice = 32
//   cols = 64B/row = 4 uint4 lanes; each dispatch's 3.2MB sub-table fits
//   every XCD L2 (hard inter-dispatch barrier = the mechanism R6/R7 lacked).
//   16 edge subgroups/wave, 2x unroll = 32 edges in flight.
// R2: fp16 message/A/B tables (absmax 4.9e-4 < 1.5e-3 threshold).
// R3: gemm1 (fp32 input) double-bf16-split MFMA (Ah.Bh+Al.Bh+Ah.Bl).
// ---------------------------------------------------------------------------

#define BSH 9                 // log2 nodes per bucket
#define BSZ (1 << BSH)        // 512 nodes per bucket
#define MSB 4096              // edges per multisplit batch/block
#define XPAD 132              // LDS row stride (floats) for fp32 gemm staging
#define HB 256                // hist blocks in fused K1

typedef __attribute__((ext_vector_type(8))) short bf16x8;
typedef __attribute__((ext_vector_type(8))) _Float16 f16x8;
typedef __attribute__((ext_vector_type(4))) float f32x4;

__device__ __forceinline__ void acc8(uint4 u, float4& lo, float4& hi) {
  float2 f0 = __half22float2(((const __half2*)&u)[0]);
  float2 f1 = __half22float2(((const __half2*)&u)[1]);
  float2 f2 = __half22float2(((const __half2*)&u)[2]);
  float2 f3 = __half22float2(((const __half2*)&u)[3]);
  lo.x += f0.x; lo.y += f0.y; lo.z += f1.x; lo.w += f1.y;
  hi.x += f2.x; hi.y += f2.y; hi.z += f3.x; hi.w += f3.y;
}

__device__ __forceinline__ float4 h4_to_f4(uint2 u) {
  float2 fa = __half22float2(*(__half2*)&u.x);
  float2 fb = __half22float2(*(__half2*)&u.y);
  return make_float4(fa.x, fa.y, fb.x, fb.y);
}

// Exact fp32 -> bf16 hi/lo split.
__device__ __forceinline__ void split8(const float* v, bf16x8& hi, bf16x8& lo) {
#pragma unroll
  for (int j = 0; j < 8; ++j) {
    unsigned u = __float_as_uint(v[j]);
    hi[j] = (short)(u >> 16);
    float lf = v[j] - __uint_as_float(u & 0xffff0000u);
    lo[j] = (short)(__float_as_uint(lf) >> 16);
  }
}

// K1: weight fragment prep UNION dst bucket-histogram (both CSR-independent;
// gcnt/gcur pre-zeroed by hipMemsetAsync).
__global__ __launch_bounds__(256) void k_prep_hist(
    const float* __restrict__ W1, const float* __restrict__ W2,
    const float* __restrict__ Wh1, short* __restrict__ fragH,
    short* __restrict__ fragL,
    const int* __restrict__ dst, int* __restrict__ gcnt, int e, int kb) {
  if (blockIdx.x >= 32) {
    __shared__ int h4[512];
    int bid = blockIdx.x - 32;
    int tid = threadIdx.x, wid = tid >> 6;
    for (int t = tid; t < 512; t += 256) h4[t] = 0;
    __syncthreads();
    for (int i = bid * 256 + tid; i < e; i += HB * 256) {
      int d = __builtin_nontemporal_load(&dst[i]);
      atomicAdd(&h4[wid * 128 + (d >> BSH)], 1);
    }
    __syncthreads();
    if (tid < kb)
      atomicAdd(&gcnt[tid], h4[tid] + h4[128 + tid] + h4[256 + tid] + h4[384 + tid]);
    return;
  }
  int g = blockIdx.x * 256 + threadIdx.x;
  int w = g >> 11;
  int rem = g & 2047;
  int lane = rem & 63;
  int ts = rem >> 6;
  int t = ts >> 2, s = ts & 3;
  int n = (t << 4) + (lane & 15);
  int k0 = s * 32 + (lane >> 4) * 8;
  const float* W = (w == 0) ? W1 : (w == 1) ? W2 : (w == 2) ? Wh1 : (Wh1 + 128 * 128);
  short h[8], l[8];
#pragma unroll
  for (int j = 0; j < 8; ++j) {
    float x = W[(k0 + j) * 128 + n];
    if (w == 0) {
      unsigned u = __float_as_uint(x);
      h[j] = (short)(u >> 16);
      float lf = x - __uint_as_float(u & 0xffff0000u);
      l[j] = (short)(__float_as_uint(lf) >> 16);
    } else {
      __half hh = __float2half(x);
      h[j] = __half_as_short(hh);
      l[j] = __half_as_short(__float2half(x - __half2float(hh)));
    }
  }
  ((int4*)fragH)[g] = *(int4*)h;
  ((int4*)fragL)[g] = *(int4*)l;
}

// fp32-input MFMA GEMM: C16 = fp16(rowscale * X@W1), bf16 split, LDS-staged.
__global__ __launch_bounds__(256) void k_gemm_mfma(
    const float* __restrict__ X, const short* __restrict__ fragH,
    const short* __restrict__ fragL, const float* __restrict__ rowscale,
    __half* __restrict__ C16, int n) {
  __shared__ float sX[64 * XPAD];
  int tid = threadIdx.x;
  int row0 = blockIdx.x * 64;
  const float2* X2 = (const float2*)(X + (size_t)row0 * 128);
#pragma unroll
  for (int it = 0; it < 16; ++it) {
    int t = it * 256 + tid;
    int r = t >> 6, c2 = t & 63;
    int gr = row0 + r;
    float2 v = (gr < n) ? X2[t] : make_float2(0.f, 0.f);
    *(float2*)&sX[r * XPAD + c2 * 2] = v;
  }
  __syncthreads();
  int wid = tid >> 6, lane = tid & 63;
  int r0 = row0 + wid * 16;
  if (r0 >= n) return;
  int m = lane & 15, quad = lane >> 4;
  const float* xrow = sX + (wid * 16 + m) * XPAD;
  f32x4 acc[8];
#pragma unroll
  for (int t = 0; t < 8; ++t) acc[t] = (f32x4)(0.f);
  const int4* FH = (const int4*)fragH;
  const int4* FL = (const int4*)fragL;
#pragma unroll
  for (int s = 0; s < 4; ++s) {
    int k0 = s * 32 + quad * 8;
    float xv[8];
    *(float2*)&xv[0] = *(const float2*)(xrow + k0);
    *(float2*)&xv[2] = *(const float2*)(xrow + k0 + 2);
    *(float2*)&xv[4] = *(const float2*)(xrow + k0 + 4);
    *(float2*)&xv[6] = *(const float2*)(xrow + k0 + 6);
    bf16x8 ah, al;
    split8(xv, ah, al);
#pragma unroll
    for (int t = 0; t < 8; ++t) {
      int idx = (t * 4 + s) * 64 + lane;
      bf16x8 bh = *(const bf16x8*)&FH[idx];
      bf16x8 bl = *(const bf16x8*)&FL[idx];
      acc[t] = __builtin_amdgcn_mfma_f32_16x16x32_bf16(ah, bh, acc[t], 0, 0, 0);
      acc[t] = __builtin_amdgcn_mfma_f32_16x16x32_bf16(al, bh, acc[t], 0, 0, 0);
      acc[t] = __builtin_amdgcn_mfma_f32_16x16x32_bf16(ah, bl, acc[t], 0, 0, 0);
    }
  }
  float sc[4];
#pragma unroll
  for (int r = 0; r < 4; ++r)
    sc[r] = rowscale[r0 + quad * 4 + r];
#pragma unroll
  for (int t = 0; t < 8; ++t) {
#pragma unroll
    for (int r = 0; r < 4; ++r) {
      int row = r0 + quad * 4 + r;
      C16[(size_t)row * 128 + t * 16 + m] = __float2half(acc[t][r] * sc[r]);
    }
  }
}

// f16-input GEMM: C16 = fp16(rowscale * X16 @ W), A fp16-exact, B f16 hi+lo.
__global__ __launch_bounds__(256) void k_gemm_f16(
    const __half* __restrict__ X16, const short* __restrict__ fragH,
    const short* __restrict__ fragL, const float* __restrict__ rowscale,
    __half* __restrict__ C16, int n) {
  int wid = threadIdx.x >> 6, lane = threadIdx.x & 63;
  int r0 = (blockIdx.x * 4 + wid) * 16;
  if (r0 >= n) return;
  int m = lane & 15, quad = lane >> 4;
  const uint4* Xr = (const uint4*)(X16 + (size_t)(r0 + m) * 128);
  f32x4 acc[8];
#pragma unroll
  for (int t = 0; t < 8; ++t) acc[t] = (f32x4)(0.f);
  const int4* FH = (const int4*)fragH;
  const int4* FL = (const int4*)fragL;
#pragma unroll
  for (int s = 0; s < 4; ++s) {
    uint4 av = Xr[quad + 4 * s];
    f16x8 a = *(const f16x8*)&av;
#pragma unroll
    for (int t = 0; t < 8; ++t) {
      int idx = (t * 4 + s) * 64 + lane;
      int4 bhv = FH[idx], blv = FL[idx];
      f16x8 bh = *(const f16x8*)&bhv;
      f16x8 bl = *(const f16x8*)&blv;
      acc[t] = __builtin_amdgcn_mfma_f32_16x16x32_f16(a, bh, acc[t], 0, 0, 0);
      acc[t] = __builtin_amdgcn_mfma_f32_16x16x32_f16(a, bl, acc[t], 0, 0, 0);
    }
  }
  float sc[4];
#pragma unroll
  for (int r = 0; r < 4; ++r)
    sc[r] = rowscale ? rowscale[r0 + quad * 4 + r] : 1.f;
#pragma unroll
  for (int t = 0; t < 8; ++t) {
#pragma unroll
    for (int r = 0; r < 4; ++r) {
      int row = r0 + quad * 4 + r;
      C16[(size_t)row * 128 + t * 16 + m] = __float2half(acc[t][r] * sc[r]);
    }
  }
}

// Dual-output f16 GEMM for the head (reads X16 once; no rowscale).
__global__ __launch_bounds__(256) void k_gemm_dual_f16(
    const __half* __restrict__ X16,
    const short* __restrict__ fHa, const short* __restrict__ fLa,
    const short* __restrict__ fHb, const short* __restrict__ fLb,
    __half* __restrict__ A16, __half* __restrict__ B16, int n) {
  int wid = threadIdx.x >> 6, lane = threadIdx.x & 63;
  int r0 = (blockIdx.x * 4 + wid) * 16;
  if (r0 >= n) return;
  int m = lane & 15, quad = lane >> 4;
  const uint4* Xr = (const uint4*)(X16 + (size_t)(r0 + m) * 128);
  f32x4 accA[8], accB[8];
#pragma unroll
  for (int t = 0; t < 8; ++t) { accA[t] = (f32x4)(0.f); accB[t] = (f32x4)(0.f); }
  const int4* FHa = (const int4*)fHa; const int4* FLa = (const int4*)fLa;
  const int4* FHb = (const int4*)fHb; const int4* FLb = (const int4*)fLb;
#pragma unroll
  for (int s = 0; s < 4; ++s) {
    uint4 av = Xr[quad + 4 * s];
    f16x8 a = *(const f16x8*)&av;
#pragma unroll
    for (int t = 0; t < 8; ++t) {
      int idx = (t * 4 + s) * 64 + lane;
      int4 v0 = FHa[idx], v1 = FLa[idx], v2 = FHb[idx], v3 = FLb[idx];
      accA[t] = __builtin_amdgcn_mfma_f32_16x16x32_f16(a, *(const f16x8*)&v0, accA[t], 0, 0, 0);
      accA[t] = __builtin_amdgcn_mfma_f32_16x16x32_f16(a, *(const f16x8*)&v1, accA[t], 0, 0, 0);
      accB[t] = __builtin_amdgcn_mfma_f32_16x16x32_f16(a, *(const f16x8*)&v2, accB[t], 0, 0, 0);
      accB[t] = __builtin_amdgcn_mfma_f32_16x16x32_f16(a, *(const f16x8*)&v3, accB[t], 0, 0, 0);
    }
  }
#pragma unroll
  for (int t = 0; t < 8; ++t) {
#pragma unroll
    for (int r = 0; r < 4; ++r) {
      int row = r0 + quad * 4 + r;
      A16[(size_t)row * 128 + t * 16 + m] = __float2half(accA[t][r]);
      B16[(size_t)row * 128 + t * 16 + m] = __float2half(accB[t][r]);
    }
  }
}

// multisplit: per-wave replicated LDS hist; in-block scan of gcnt; one global
// atomic per bucket per batch. packed = (d_local<<16)|src  [src < 65536]
__global__ __launch_bounds__(256) void k_multisplit(const int* __restrict__ src,
                                                    const int* __restrict__ dst,
                                                    const int* __restrict__ gcnt,
                                                    int* __restrict__ gcur,
                                                    int* __restrict__ tmp,
                                                    int e, int kb) {
  __shared__ int h4[4 * 128], off[4 * 128], sbase[128], ws[2];
  int tid = threadIdx.x, wid = tid >> 6, lane = tid & 63;
  for (int t = tid; t < 512; t += 256) h4[t] = 0;
  __syncthreads();
  int i0 = blockIdx.x * MSB + tid;
  int d[16], rk[16];
#pragma unroll
  for (int u = 0; u < 16; ++u) {
    int i = i0 + u * 256;
    if (i < e) {
      d[u] = __builtin_nontemporal_load(&dst[i]);
      rk[u] = atomicAdd(&h4[wid * 128 + (d[u] >> BSH)], 1);
    }
  }
  __syncthreads();
  int tot = 0;
  if (tid < 128) {
    int c0 = h4[tid], c1 = h4[128 + tid], c2 = h4[256 + tid], c3 = h4[384 + tid];
    off[tid] = 0; off[128 + tid] = c0;
    off[256 + tid] = c0 + c1; off[384 + tid] = c0 + c1 + c2;
    tot = c0 + c1 + c2 + c3;
  }
  int v = (tid < 128 && tid < kb) ? gcnt[tid] : 0;
  int orig = v;
#pragma unroll
  for (int o = 1; o < 64; o <<= 1) {
    int u = __shfl_up(v, o, 64);
    if (lane >= o) v += u;
  }
  if (lane == 63 && wid < 2) ws[wid] = v;
  __syncthreads();
  if (tid < 128) sbase[tid] = ((wid == 1) ? ws[0] : 0) + v - orig;
  __syncthreads();
  if (tid < kb && tot > 0) sbase[tid] += atomicAdd(&gcur[tid], tot);
  __syncthreads();
#pragma unroll
  for (int u = 0; u < 16; ++u) {
    int i = i0 + u * 256;
    if (i < e) {
      int s = __builtin_nontemporal_load(&src[i]);
      int k = d[u] >> BSH;
      tmp[sbase[k] + off[wid * 128 + k] + rk[u]] = ((d[u] & (BSZ - 1)) << 16) | s;
    }
  }
}

// one block per bucket: in-block scan of gcnt; per-node degree + scan +
// cursor scatter in LDS. colarr u16, bucket-local (no write-amp).
__global__ __launch_bounds__(512) void k_bucket_build(
    const int* __restrict__ tmp, const int* __restrict__ gcnt,
    int* __restrict__ rowptr, float* __restrict__ dinv,
    unsigned short* __restrict__ colarr, int n, int kb, int e) {
  __shared__ int dl[BSZ], cl[BSZ], sbase[128], ws[8];
  int t = threadIdx.x, b = blockIdx.x;
  int lane = t & 63, w = t >> 6;
  int v = (t < 128 && t < kb) ? gcnt[t] : 0;
  int orig0 = v;
#pragma unroll
  for (int o = 1; o < 64; o <<= 1) {
    int u = __shfl_up(v, o, 64);
    if (lane >= o) v += u;
  }
  if (lane == 63 && w < 2) ws[w] = v;
  dl[t] = 0;
  __syncthreads();
  if (t < 128) sbase[t] = ((w == 1) ? ws[0] : 0) + v - orig0;
  __syncthreads();
  int s0 = sbase[b];
  int s1 = s0 + gcnt[b];
  for (int j = s0 + t; j < s1; j += 512)
    atomicAdd(&dl[((unsigned)tmp[j]) >> 16], 1);
  __syncthreads();
  int dv = dl[t], orig = dv;
#pragma unroll
  for (int o = 1; o < 64; o <<= 1) {
    int u = __shfl_up(dv, o, 64);
    if (lane >= o) dv += u;
  }
  if (lane == 63) ws[w] = dv;
  __syncthreads();
  if (t == 0) {
    int a = 0;
#pragma unroll
    for (int k = 0; k < 8; ++k) { int x = ws[k]; ws[k] = a; a += x; }
  }
  __syncthreads();
  int ex = ws[w] + dv - orig;
  cl[t] = ex;
  int node = (b << BSH) + t;
  if (node < n) {
    rowptr[node] = s0 + ex;
    dinv[node] = rsqrtf((float)(orig + 1));  // +1 self loop
  }
  if (b == kb - 1 && t == 0) rowptr[n] = e;
  __syncthreads();
  for (int j = s0 + t; j < s1; j += 512) {
    int p = tmp[j];
    int r = atomicAdd(&cl[((unsigned)p) >> 16], 1);
    colarr[s0 + r] = (unsigned short)(p & 0xFFFF);
  }
}

// Sliced aggregation, ONE SLICE PER DISPATCH (hard barrier between slices):
// slice = 32 cols = 64B/row = 4 uint4 lanes. Wave = 16 edge subgroups x
// 4 lanes; 2x unroll = 32 edges in flight. Sub-table (3.2MB) fits XCD L2.
// out16[i,sl] = fp16(relu(dinv[i]*(g[i,sl] + sum g[col,sl]) + bias[sl]))
__global__ __launch_bounds__(256) void k_agg_slice(
    const uint4* __restrict__ G, const float* __restrict__ dinv,
    const int* __restrict__ rowptr, const unsigned short* __restrict__ col,
    const float* __restrict__ bias, uint4* __restrict__ out16, int n,
    int slice) {
  int i = blockIdx.x * 4 + (threadIdx.x >> 6);
  if (i >= n) return;
  int lane = threadIdx.x & 63;
  int eg = lane >> 2;          // edge subgroup 0..15
  int c4 = lane & 3;           // uint4 within slice
  int base = slice * 4 + c4;   // uint4 index within row (0..15)
  float4 z = make_float4(0.f, 0.f, 0.f, 0.f);
  float4 lo0 = z, hi0 = z, lo1 = z, hi1 = z;
  if (eg == 0) acc8(G[(size_t)i * 16 + base], lo0, hi0);  // self loop once
  int beg = rowptr[i], end = rowptr[i + 1];
  int j = beg;
  for (; j + 32 <= end; j += 32) {
    int s0 = __builtin_nontemporal_load(&col[j + eg]);
    int s1 = __builtin_nontemporal_load(&col[j + 16 + eg]);
    uint4 u0 = G[(size_t)s0 * 16 + base];
    uint4 u1 = G[(size_t)s1 * 16 + base];
    acc8(u0, lo0, hi0); acc8(u1, lo1, hi1);
  }
  for (; j + 16 <= end; j += 16) {
    int s0 = __builtin_nontemporal_load(&col[j + eg]);
    acc8(G[(size_t)s0 * 16 + base], lo0, hi0);
  }
  int rem = end - j;
  if (eg < rem) {
    int s0 = __builtin_nontemporal_load(&col[j + eg]);
    acc8(G[(size_t)s0 * 16 + base], lo1, hi1);
  }
  float4 lo, hi;
  lo.x = lo0.x + lo1.x; lo.y = lo0.y + lo1.y;
  lo.z = lo0.z + lo1.z; lo.w = lo0.w + lo1.w;
  hi.x = hi0.x + hi1.x; hi.y = hi0.y + hi1.y;
  hi.z = hi0.z + hi1.z; hi.w = hi0.w + hi1.w;
#pragma unroll
  for (int o = 32; o >= 4; o >>= 1) {
    lo.x += __shfl_down(lo.x, o, 64);
    lo.y += __shfl_down(lo.y, o, 64);
    lo.z += __shfl_down(lo.z, o, 64);
    lo.w += __shfl_down(lo.w, o, 64);
    hi.x += __shfl_down(hi.x, o, 64);
    hi.y += __shfl_down(hi.y, o, 64);
    hi.z += __shfl_down(hi.z, o, 64);
    hi.w += __shfl_down(hi.w, o, 64);
  }
  if (eg == 0) {
    float di = dinv[i];
    float4 b0 = ((const float4*)bias)[2 * base];
    float4 b1 = ((const float4*)bias)[2 * base + 1];
    __half2 q0 = __floats2half2_rn(fmaxf(fmaf(di, lo.x, b0.x), 0.f),
                                   fmaxf(fmaf(di, lo.y, b0.y), 0.f));
    __half2 q1 = __floats2half2_rn(fmaxf(fmaf(di, lo.z, b0.z), 0.f),
                                   fmaxf(fmaf(di, lo.w, b0.w), 0.f));
    __half2 q2 = __floats2half2_rn(fmaxf(fmaf(di, hi.x, b1.x), 0.f),
                                   fmaxf(fmaf(di, hi.y, b1.y), 0.f));
    __half2 q3 = __floats2half2_rn(fmaxf(fmaf(di, hi.z, b1.z), 0.f),
                                   fmaxf(fmaf(di, hi.w, b1.w), 0.f));
    uint4 o;
    o.x = *(unsigned*)&q0; o.y = *(unsigned*)&q1;
    o.z = *(unsigned*)&q2; o.w = *(unsigned*)&q3;
    out16[(size_t)i * 16 + base] = o;
  }
}

// one wave per pair: sub0 loads A[p0] half4, sub1 loads B[p1] half4;
// combine via shfl_xor(32), dot with wh2, reduce.
__global__ __launch_bounds__(256) void k_pairs_h(
    const __half2* __restrict__ A, const __half2* __restrict__ B,
    const int* __restrict__ pairs, const float* __restrict__ bh1,
    const float* __restrict__ wh2, const float* __restrict__ bh2,
    float* __restrict__ out, int P) {
  int p = blockIdx.x * 4 + (threadIdx.x >> 6);
  int lane = threadIdx.x & 63;
  if (p >= P) return;
  int sub = lane >> 5, c4 = lane & 31;
  int p0 = pairs[2 * p], p1 = pairs[2 * p + 1];
  const uint2* T4 = sub ? (const uint2*)B : (const uint2*)A;
  int row = sub ? p1 : p0;
  float4 v = h4_to_f4(T4[(size_t)row * 32 + c4]);
  v.x += __shfl_xor(v.x, 32, 64);
  v.y += __shfl_xor(v.y, 32, 64);
  v.z += __shfl_xor(v.z, 32, 64);
  v.w += __shfl_xor(v.w, 32, 64);
  float4 bi = ((const float4*)bh1)[c4];
  float4 wv = ((const float4*)wh2)[c4];
  float s = fmaxf(v.x + bi.x, 0.f) * wv.x + fmaxf(v.y + bi.y, 0.f) * wv.y +
            fmaxf(v.z + bi.z, 0.f) * wv.z + fmaxf(v.w + bi.w, 0.f) * wv.w;
#pragma unroll
  for (int o = 16; o > 0; o >>= 1) s += __shfl_down(s, o, 64);
  if (lane == 0) out[p] = s + bh2[0];
}

extern "C" void kernel_launch(void* const* d_in, const int* in_sizes, int n_in,
                              void* d_out, int out_size, void* d_ws, size_t ws_size,
                              hipStream_t stream) {
  const float* x   = (const float*)d_in[0];
  const int* ei    = (const int*)d_in[1];
  const int* pairs = (const int*)d_in[2];
  const float* W1  = (const float*)d_in[3];
  const float* b1  = (const float*)d_in[4];
  const float* W2  = (const float*)d_in[5];
  const float* b2  = (const float*)d_in[6];
  const float* Wh1 = (const float*)d_in[7];
  const float* bh1 = (const float*)d_in[8];
  const float* Wh2 = (const float*)d_in[9];
  const float* bh2 = (const float*)d_in[10];
  (void)n_in; (void)out_size; (void)ws_size;

  int N = in_sizes[0] / 128;
  int E = in_sizes[1] / 2;
  int P = in_sizes[2] / 2;
  const int* src = ei;
  const int* dst = ei + E;
  int KB = (N + BSZ - 1) >> BSH;  // buckets (98 for N=50000)

  char* wsp = (char*)d_ws;
  size_t off = 0;
  auto alloc = [&](size_t bytes) -> void* {
    void* p = wsp + off;
    off += (bytes + 255) & ~(size_t)255;
    return p;
  };
  __half* g16 = (__half*)alloc((size_t)N * 128 * 2);  // messages; reused as A16
  __half* h1  = (__half*)alloc((size_t)N * 128 * 2);  // fp16; reused as B16
  __half* h2  = (__half*)alloc((size_t)N * 128 * 2);  // fp16
  float* dinv = (float*)alloc((size_t)N * 4);
  int* rowptr = (int*)alloc((size_t)(N + 1) * 4);
  unsigned short* colarr = (unsigned short*)alloc((size_t)E * 2);
  int* tmp    = (int*)alloc((size_t)E * 4);
  short* fragH = (short*)alloc(4 * 2048 * 8 * 2);     // 128KB
  short* fragL = (short*)alloc(4 * 2048 * 8 * 2);     // 128KB
  int* gcnt  = (int*)alloc((size_t)(KB + 1) * 4);
  int* gcur  = (int*)alloc((size_t)(KB + 1) * 4);
  __half* A16 = g16;            // g16 dead by the time head runs
  __half* B16 = h1;             // h1 dead after conv2 gemm
  short* fH_W1 = fragH + 0 * 16384;  short* fL_W1 = fragL + 0 * 16384;
  short* fH_W2 = fragH + 1 * 16384;  short* fL_W2 = fragL + 1 * 16384;
  short* fH_Wa = fragH + 2 * 16384;  short* fL_Wa = fragL + 2 * 16384;
  short* fH_Wb = fragH + 3 * 16384;  short* fL_Wb = fragL + 3 * 16384;

  int GB = (N + 63) / 64;          // fp32 gemm: 64 rows per block
  int GF = (N / 16 + 3) / 4;       // f16 gemm: 16 rows/wave, 4 waves/block
  int AB = (N + 3) / 4;            // agg: 4 rows per block

  // zero bucket counters, then fused prep+hist
  hipMemsetAsync(gcnt, 0, (size_t)(KB + 1) * 4, stream);
  hipMemsetAsync(gcur, 0, (size_t)(KB + 1) * 4, stream);
  k_prep_hist<<<32 + HB, 256, 0, stream>>>(W1, W2, Wh1, fragH, fragL,
                                           dst, gcnt, E, KB);
  // CSR build
  k_multisplit<<<(E + MSB - 1) / MSB, 256, 0, stream>>>(src, dst, gcnt, gcur,
                                                        tmp, E, KB);
  k_bucket_build<<<KB, 512, 0, stream>>>(tmp, gcnt, rowptr, dinv, colarr, N, KB, E);
  // conv1 (gemm pre-scales with dinv)
  k_gemm_mfma<<<GB, 256, 0, stream>>>(x, fH_W1, fL_W1, dinv, g16, N);
  for (int sl = 0; sl < 4; ++sl)
    k_agg_slice<<<AB, 256, 0, stream>>>((const uint4*)g16, dinv, rowptr,
                                        colarr, b1, (uint4*)h1, N, sl);
  // conv2 (f16 path)
  k_gemm_f16<<<GF, 256, 0, stream>>>(h1, fH_W2, fL_W2, dinv, g16, N);
  for (int sl = 0; sl < 4; ++sl)
    k_agg_slice<<<AB, 256, 0, stream>>>((const uint4*)g16, dinv, rowptr,
                                        colarr, b2, (uint4*)h2, N, sl);
  // head
  k_gemm_dual_f16<<<GF, 256, 0, stream>>>(h2, fH_Wa, fL_Wa, fH_Wb, fL_Wb,
                                          A16, B16, N);
  k_pairs_h<<<(P + 3) / 4, 256, 0, stream>>>((const __half2*)A16, (const __half2*)B16,
                                             pairs, bh1, Wh2, bh2, (float*)d_out, P);
}

// Round 16
// 353.175 us; speedup vs baseline: 1.3794x; 1.3794x over previous
//
#include <hip/hip_runtime.h>
#include <hip/hip_fp16.h>

// ---------------------------------------------------------------------------
// LinkPredictionGNN: 2x GCNConv (self-loops, sym-norm) + pair MLP head.
//   memset gcnt/gcur -> K1 prep_w UNION hist -> K2 multisplit -> K3 bucket
//   K4 gemm1 (fp32 x, bf16-split, rowscale=dinv) -> K5 agg1 (fp16 out)
//   K6 gemm2_f16 -> K7 agg2 -> K8 gemm_dual_f16 -> K9 pairs
//
// R1/R4: random 4B global writes/atomics -> ~10x line-writeback amp.
// R5: CSR build = 2-level bucket sort, zero global random atomics.
// R6/R7/R14 ALL FAILED (L2-locality for the agg gather): blockIdx%k slices,
//   slice-major grid, and slice-per-dispatch each made it worse. The ~60us
//   monolithic agg (~155MB L2-miss @ ~2.8TB/s) is the floor. Do not retry.
// R8: fp32 gemm X-tile staged via coalesced float2->LDS.
// R12 FAILED: per-edge dinv[src] in agg broke pipelining; R13 reverted
//   normalization to gemm1 epilogue; kept fp16 h1/h2 + f16 2-MFMA GEMMs.
// R15: pairs kernel widened: uint4 lanes (256B row / 16 lanes), A/B/A'/B'
//   across 4 subgroups = 2 pairs per load instr, 2x unroll = 4 pairs/wave
//   (2KB in flight vs 512B) — same MLP recipe that fixed agg in R9.
// R2: fp16 message/A/B tables (absmax 4.9e-4 < 1.5e-3 threshold).
// R3: gemm1 (fp32 input) double-bf16-split MFMA (Ah.Bh+Al.Bh+Ah.Bl).
// ---------------------------------------------------------------------------

#define BSH 9                 // log2 nodes per bucket
#define BSZ (1 << BSH)        // 512 nodes per bucket
#define MSB 4096              // edges per multisplit batch/block
#define XPAD 132              // LDS row stride (floats) for fp32 gemm staging
#define HB 256                // hist blocks in fused K1

typedef __attribute__((ext_vector_type(8))) short bf16x8;
typedef __attribute__((ext_vector_type(8))) _Float16 f16x8;
typedef __attribute__((ext_vector_type(4))) float f32x4;

__device__ __forceinline__ void acc8(uint4 u, float4& lo, float4& hi) {
  float2 f0 = __half22float2(((const __half2*)&u)[0]);
  float2 f1 = __half22float2(((const __half2*)&u)[1]);
  float2 f2 = __half22float2(((const __half2*)&u)[2]);
  float2 f3 = __half22float2(((const __half2*)&u)[3]);
  lo.x += f0.x; lo.y += f0.y; lo.z += f1.x; lo.w += f1.y;
  hi.x += f2.x; hi.y += f2.y; hi.z += f3.x; hi.w += f3.y;
}

// Exact fp32 -> bf16 hi/lo split.
__device__ __forceinline__ void split8(const float* v, bf16x8& hi, bf16x8& lo) {
#pragma unroll
  for (int j = 0; j < 8; ++j) {
    unsigned u = __float_as_uint(v[j]);
    hi[j] = (short)(u >> 16);
    float lf = v[j] - __uint_as_float(u & 0xffff0000u);
    lo[j] = (short)(__float_as_uint(lf) >> 16);
  }
}

// K1: weight fragment prep UNION dst bucket-histogram (both CSR-independent;
// gcnt/gcur pre-zeroed by hipMemsetAsync).
__global__ __launch_bounds__(256) void k_prep_hist(
    const float* __restrict__ W1, const float* __restrict__ W2,
    const float* __restrict__ Wh1, short* __restrict__ fragH,
    short* __restrict__ fragL,
    const int* __restrict__ dst, int* __restrict__ gcnt, int e, int kb) {
  if (blockIdx.x >= 32) {
    __shared__ int h4[512];
    int bid = blockIdx.x - 32;
    int tid = threadIdx.x, wid = tid >> 6;
    for (int t = tid; t < 512; t += 256) h4[t] = 0;
    __syncthreads();
    for (int i = bid * 256 + tid; i < e; i += HB * 256) {
      int d = __builtin_nontemporal_load(&dst[i]);
      atomicAdd(&h4[wid * 128 + (d >> BSH)], 1);
    }
    __syncthreads();
    if (tid < kb)
      atomicAdd(&gcnt[tid], h4[tid] + h4[128 + tid] + h4[256 + tid] + h4[384 + tid]);
    return;
  }
  int g = blockIdx.x * 256 + threadIdx.x;
  int w = g >> 11;
  int rem = g & 2047;
  int lane = rem & 63;
  int ts = rem >> 6;
  int t = ts >> 2, s = ts & 3;
  int n = (t << 4) + (lane & 15);
  int k0 = s * 32 + (lane >> 4) * 8;
  const float* W = (w == 0) ? W1 : (w == 1) ? W2 : (w == 2) ? Wh1 : (Wh1 + 128 * 128);
  short h[8], l[8];
#pragma unroll
  for (int j = 0; j < 8; ++j) {
    float x = W[(k0 + j) * 128 + n];
    if (w == 0) {
      unsigned u = __float_as_uint(x);
      h[j] = (short)(u >> 16);
      float lf = x - __uint_as_float(u & 0xffff0000u);
      l[j] = (short)(__float_as_uint(lf) >> 16);
    } else {
      __half hh = __float2half(x);
      h[j] = __half_as_short(hh);
      l[j] = __half_as_short(__float2half(x - __half2float(hh)));
    }
  }
  ((int4*)fragH)[g] = *(int4*)h;
  ((int4*)fragL)[g] = *(int4*)l;
}

// fp32-input MFMA GEMM: C16 = fp16(rowscale * X@W1), bf16 split, LDS-staged.
__global__ __launch_bounds__(256) void k_gemm_mfma(
    const float* __restrict__ X, const short* __restrict__ fragH,
    const short* __restrict__ fragL, const float* __restrict__ rowscale,
    __half* __restrict__ C16, int n) {
  __shared__ float sX[64 * XPAD];
  int tid = threadIdx.x;
  int row0 = blockIdx.x * 64;
  const float2* X2 = (const float2*)(X + (size_t)row0 * 128);
#pragma unroll
  for (int it = 0; it < 16; ++it) {
    int t = it * 256 + tid;
    int r = t >> 6, c2 = t & 63;
    int gr = row0 + r;
    float2 v = (gr < n) ? X2[t] : make_float2(0.f, 0.f);
    *(float2*)&sX[r * XPAD + c2 * 2] = v;
  }
  __syncthreads();
  int wid = tid >> 6, lane = tid & 63;
  int r0 = row0 + wid * 16;
  if (r0 >= n) return;
  int m = lane & 15, quad = lane >> 4;
  const float* xrow = sX + (wid * 16 + m) * XPAD;
  f32x4 acc[8];
#pragma unroll
  for (int t = 0; t < 8; ++t) acc[t] = (f32x4)(0.f);
  const int4* FH = (const int4*)fragH;
  const int4* FL = (const int4*)fragL;
#pragma unroll
  for (int s = 0; s < 4; ++s) {
    int k0 = s * 32 + quad * 8;
    float xv[8];
    *(float2*)&xv[0] = *(const float2*)(xrow + k0);
    *(float2*)&xv[2] = *(const float2*)(xrow + k0 + 2);
    *(float2*)&xv[4] = *(const float2*)(xrow + k0 + 4);
    *(float2*)&xv[6] = *(const float2*)(xrow + k0 + 6);
    bf16x8 ah, al;
    split8(xv, ah, al);
#pragma unroll
    for (int t = 0; t < 8; ++t) {
      int idx = (t * 4 + s) * 64 + lane;
      bf16x8 bh = *(const bf16x8*)&FH[idx];
      bf16x8 bl = *(const bf16x8*)&FL[idx];
      acc[t] = __builtin_amdgcn_mfma_f32_16x16x32_bf16(ah, bh, acc[t], 0, 0, 0);
      acc[t] = __builtin_amdgcn_mfma_f32_16x16x32_bf16(al, bh, acc[t], 0, 0, 0);
      acc[t] = __builtin_amdgcn_mfma_f32_16x16x32_bf16(ah, bl, acc[t], 0, 0, 0);
    }
  }
  float sc[4];
#pragma unroll
  for (int r = 0; r < 4; ++r)
    sc[r] = rowscale[r0 + quad * 4 + r];
#pragma unroll
  for (int t = 0; t < 8; ++t) {
#pragma unroll
    for (int r = 0; r < 4; ++r) {
      int row = r0 + quad * 4 + r;
      C16[(size_t)row * 128 + t * 16 + m] = __float2half(acc[t][r] * sc[r]);
    }
  }
}

// f16-input GEMM: C16 = fp16(rowscale * X16 @ W), A fp16-exact, B f16 hi+lo.
__global__ __launch_bounds__(256) void k_gemm_f16(
    const __half* __restrict__ X16, const short* __restrict__ fragH,
    const short* __restrict__ fragL, const float* __restrict__ rowscale,
    __half* __restrict__ C16, int n) {
  int wid = threadIdx.x >> 6, lane = threadIdx.x & 63;
  int r0 = (blockIdx.x * 4 + wid) * 16;
  if (r0 >= n) return;
  int m = lane & 15, quad = lane >> 4;
  const uint4* Xr = (const uint4*)(X16 + (size_t)(r0 + m) * 128);
  f32x4 acc[8];
#pragma unroll
  for (int t = 0; t < 8; ++t) acc[t] = (f32x4)(0.f);
  const int4* FH = (const int4*)fragH;
  const int4* FL = (const int4*)fragL;
#pragma unroll
  for (int s = 0; s < 4; ++s) {
    uint4 av = Xr[quad + 4 * s];
    f16x8 a = *(const f16x8*)&av;
#pragma unroll
    for (int t = 0; t < 8; ++t) {
      int idx = (t * 4 + s) * 64 + lane;
      int4 bhv = FH[idx], blv = FL[idx];
      f16x8 bh = *(const f16x8*)&bhv;
      f16x8 bl = *(const f16x8*)&blv;
      acc[t] = __builtin_amdgcn_mfma_f32_16x16x32_f16(a, bh, acc[t], 0, 0, 0);
      acc[t] = __builtin_amdgcn_mfma_f32_16x16x32_f16(a, bl, acc[t], 0, 0, 0);
    }
  }
  float sc[4];
#pragma unroll
  for (int r = 0; r < 4; ++r)
    sc[r] = rowscale ? rowscale[r0 + quad * 4 + r] : 1.f;
#pragma unroll
  for (int t = 0; t < 8; ++t) {
#pragma unroll
    for (int r = 0; r < 4; ++r) {
      int row = r0 + quad * 4 + r;
      C16[(size_t)row * 128 + t * 16 + m] = __float2half(acc[t][r] * sc[r]);
    }
  }
}

// Dual-output f16 GEMM for the head (reads X16 once; no rowscale).
__global__ __launch_bounds__(256) void k_gemm_dual_f16(
    const __half* __restrict__ X16,
    const short* __restrict__ fHa, const short* __restrict__ fLa,
    const short* __restrict__ fHb, const short* __restrict__ fLb,
    __half* __restrict__ A16, __half* __restrict__ B16, int n) {
  int wid = threadIdx.x >> 6, lane = threadIdx.x & 63;
  int r0 = (blockIdx.x * 4 + wid) * 16;
  if (r0 >= n) return;
  int m = lane & 15, quad = lane >> 4;
  const uint4* Xr = (const uint4*)(X16 + (size_t)(r0 + m) * 128);
  f32x4 accA[8], accB[8];
#pragma unroll
  for (int t = 0; t < 8; ++t) { accA[t] = (f32x4)(0.f); accB[t] = (f32x4)(0.f); }
  const int4* FHa = (const int4*)fHa; const int4* FLa = (const int4*)fLa;
  const int4* FHb = (const int4*)fHb; const int4* FLb = (const int4*)fLb;
#pragma unroll
  for (int s = 0; s < 4; ++s) {
    uint4 av = Xr[quad + 4 * s];
    f16x8 a = *(const f16x8*)&av;
#pragma unroll
    for (int t = 0; t < 8; ++t) {
      int idx = (t * 4 + s) * 64 + lane;
      int4 v0 = FHa[idx], v1 = FLa[idx], v2 = FHb[idx], v3 = FLb[idx];
      accA[t] = __builtin_amdgcn_mfma_f32_16x16x32_f16(a, *(const f16x8*)&v0, accA[t], 0, 0, 0);
      accA[t] = __builtin_amdgcn_mfma_f32_16x16x32_f16(a, *(const f16x8*)&v1, accA[t], 0, 0, 0);
      accB[t] = __builtin_amdgcn_mfma_f32_16x16x32_f16(a, *(const f16x8*)&v2, accB[t], 0, 0, 0);
      accB[t] = __builtin_amdgcn_mfma_f32_16x16x32_f16(a, *(const f16x8*)&v3, accB[t], 0, 0, 0);
    }
  }
#pragma unroll
  for (int t = 0; t < 8; ++t) {
#pragma unroll
    for (int r = 0; r < 4; ++r) {
      int row = r0 + quad * 4 + r;
      A16[(size_t)row * 128 + t * 16 + m] = __float2half(accA[t][r]);
      B16[(size_t)row * 128 + t * 16 + m] = __float2half(accB[t][r]);
    }
  }
}

// multisplit: per-wave replicated LDS hist; in-block scan of gcnt; one global
// atomic per bucket per batch. packed = (d_local<<16)|src  [src < 65536]
__global__ __launch_bounds__(256) void k_multisplit(const int* __restrict__ src,
                                                    const int* __restrict__ dst,
                                                    const int* __restrict__ gcnt,
                                                    int* __restrict__ gcur,
                                                    int* __restrict__ tmp,
                                                    int e, int kb) {
  __shared__ int h4[4 * 128], off[4 * 128], sbase[128], ws[2];
  int tid = threadIdx.x, wid = tid >> 6, lane = tid & 63;
  for (int t = tid; t < 512; t += 256) h4[t] = 0;
  __syncthreads();
  int i0 = blockIdx.x * MSB + tid;
  int d[16], rk[16];
#pragma unroll
  for (int u = 0; u < 16; ++u) {
    int i = i0 + u * 256;
    if (i < e) {
      d[u] = __builtin_nontemporal_load(&dst[i]);
      rk[u] = atomicAdd(&h4[wid * 128 + (d[u] >> BSH)], 1);
    }
  }
  __syncthreads();
  int tot = 0;
  if (tid < 128) {
    int c0 = h4[tid], c1 = h4[128 + tid], c2 = h4[256 + tid], c3 = h4[384 + tid];
    off[tid] = 0; off[128 + tid] = c0;
    off[256 + tid] = c0 + c1; off[384 + tid] = c0 + c1 + c2;
    tot = c0 + c1 + c2 + c3;
  }
  int v = (tid < 128 && tid < kb) ? gcnt[tid] : 0;
  int orig = v;
#pragma unroll
  for (int o = 1; o < 64; o <<= 1) {
    int u = __shfl_up(v, o, 64);
    if (lane >= o) v += u;
  }
  if (lane == 63 && wid < 2) ws[wid] = v;
  __syncthreads();
  if (tid < 128) sbase[tid] = ((wid == 1) ? ws[0] : 0) + v - orig;
  __syncthreads();
  if (tid < kb && tot > 0) sbase[tid] += atomicAdd(&gcur[tid], tot);
  __syncthreads();
#pragma unroll
  for (int u = 0; u < 16; ++u) {
    int i = i0 + u * 256;
    if (i < e) {
      int s = __builtin_nontemporal_load(&src[i]);
      int k = d[u] >> BSH;
      tmp[sbase[k] + off[wid * 128 + k] + rk[u]] = ((d[u] & (BSZ - 1)) << 16) | s;
    }
  }
}

// one block per bucket: in-block scan of gcnt; per-node degree + scan +
// cursor scatter in LDS. colarr u16, bucket-local (no write-amp).
__global__ __launch_bounds__(512) void k_bucket_build(
    const int* __restrict__ tmp, const int* __restrict__ gcnt,
    int* __restrict__ rowptr, float* __restrict__ dinv,
    unsigned short* __restrict__ colarr, int n, int kb, int e) {
  __shared__ int dl[BSZ], cl[BSZ], sbase[128], ws[8];
  int t = threadIdx.x, b = blockIdx.x;
  int lane = t & 63, w = t >> 6;
  int v = (t < 128 && t < kb) ? gcnt[t] : 0;
  int orig0 = v;
#pragma unroll
  for (int o = 1; o < 64; o <<= 1) {
    int u = __shfl_up(v, o, 64);
    if (lane >= o) v += u;
  }
  if (lane == 63 && w < 2) ws[w] = v;
  dl[t] = 0;
  __syncthreads();
  if (t < 128) sbase[t] = ((w == 1) ? ws[0] : 0) + v - orig0;
  __syncthreads();
  int s0 = sbase[b];
  int s1 = s0 + gcnt[b];
  for (int j = s0 + t; j < s1; j += 512)
    atomicAdd(&dl[((unsigned)tmp[j]) >> 16], 1);
  __syncthreads();
  int dv = dl[t], orig = dv;
#pragma unroll
  for (int o = 1; o < 64; o <<= 1) {
    int u = __shfl_up(dv, o, 64);
    if (lane >= o) dv += u;
  }
  if (lane == 63) ws[w] = dv;
  __syncthreads();
  if (t == 0) {
    int a = 0;
#pragma unroll
    for (int k = 0; k < 8; ++k) { int x = ws[k]; ws[k] = a; a += x; }
  }
  __syncthreads();
  int ex = ws[w] + dv - orig;
  cl[t] = ex;
  int node = (b << BSH) + t;
  if (node < n) {
    rowptr[node] = s0 + ex;
    dinv[node] = rsqrtf((float)(orig + 1));  // +1 self loop
  }
  if (b == kb - 1 && t == 0) rowptr[n] = e;
  __syncthreads();
  for (int j = s0 + t; j < s1; j += 512) {
    int p = tmp[j];
    int r = atomicAdd(&cl[((unsigned)p) >> 16], 1);
    colarr[s0 + r] = (unsigned short)(p & 0xFFFF);
  }
}

// out16[i,:] = fp16(relu(dinv[i] * (g[i,:] + sum g[col[e],:]) + bias))
// R13 known-good monolithic gather: uint4 lanes, 4 edge subgroups, 4-deep
// unroll = 16 edges in flight. DO NOT slice (R6/R7/R14 all regressed).
__global__ __launch_bounds__(256) void k_agg_h(
    const __half2* __restrict__ g2, const float* __restrict__ dinv,
    const int* __restrict__ rowptr, const unsigned short* __restrict__ col,
    const float* __restrict__ bias, __half* __restrict__ out16, int n) {
  int i = blockIdx.x * 4 + (threadIdx.x >> 6);
  if (i >= n) return;
  int lane = threadIdx.x & 63;
  int sub = lane >> 4;
  int c8 = lane & 15;
  const uint4* G = (const uint4*)g2;
  float4 z = make_float4(0.f, 0.f, 0.f, 0.f);
  float4 lo0 = z, lo1 = z, lo2 = z, lo3 = z, hi0 = z, hi1 = z, hi2 = z, hi3 = z;
  if (sub == 0) acc8(G[(size_t)i * 16 + c8], lo0, hi0);  // self loop once
  int beg = rowptr[i], end = rowptr[i + 1];
  int j = beg;
  for (; j + 16 <= end; j += 16) {
    int s0 = __builtin_nontemporal_load(&col[j + sub]);
    int s1 = __builtin_nontemporal_load(&col[j + 4 + sub]);
    int s2 = __builtin_nontemporal_load(&col[j + 8 + sub]);
    int s3 = __builtin_nontemporal_load(&col[j + 12 + sub]);
    uint4 u0 = G[(size_t)s0 * 16 + c8];
    uint4 u1 = G[(size_t)s1 * 16 + c8];
    uint4 u2 = G[(size_t)s2 * 16 + c8];
    uint4 u3 = G[(size_t)s3 * 16 + c8];
    acc8(u0, lo0, hi0); acc8(u1, lo1, hi1);
    acc8(u2, lo2, hi2); acc8(u3, lo3, hi3);
  }
  for (; j + 4 <= end; j += 4) {
    int s0 = __builtin_nontemporal_load(&col[j + sub]);
    acc8(G[(size_t)s0 * 16 + c8], lo1, hi1);
  }
  int rem = end - j;
  if (sub < rem) {
    int s0 = __builtin_nontemporal_load(&col[j + sub]);
    acc8(G[(size_t)s0 * 16 + c8], lo2, hi2);
  }
  float4 lo, hi;
  lo.x = (lo0.x + lo1.x) + (lo2.x + lo3.x);
  lo.y = (lo0.y + lo1.y) + (lo2.y + lo3.y);
  lo.z = (lo0.z + lo1.z) + (lo2.z + lo3.z);
  lo.w = (lo0.w + lo1.w) + (lo2.w + lo3.w);
  hi.x = (hi0.x + hi1.x) + (hi2.x + hi3.x);
  hi.y = (hi0.y + hi1.y) + (hi2.y + hi3.y);
  hi.z = (hi0.z + hi1.z) + (hi2.z + hi3.z);
  hi.w = (hi0.w + hi1.w) + (hi2.w + hi3.w);
  lo.x += __shfl_down(lo.x, 32, 64); lo.x += __shfl_down(lo.x, 16, 64);
  lo.y += __shfl_down(lo.y, 32, 64); lo.y += __shfl_down(lo.y, 16, 64);
  lo.z += __shfl_down(lo.z, 32, 64); lo.z += __shfl_down(lo.z, 16, 64);
  lo.w += __shfl_down(lo.w, 32, 64); lo.w += __shfl_down(lo.w, 16, 64);
  hi.x += __shfl_down(hi.x, 32, 64); hi.x += __shfl_down(hi.x, 16, 64);
  hi.y += __shfl_down(hi.y, 32, 64); hi.y += __shfl_down(hi.y, 16, 64);
  hi.z += __shfl_down(hi.z, 32, 64); hi.z += __shfl_down(hi.z, 16, 64);
  hi.w += __shfl_down(hi.w, 32, 64); hi.w += __shfl_down(hi.w, 16, 64);
  if (sub == 0) {
    float di = dinv[i];
    float4 b0 = ((const float4*)bias)[2 * c8];
    float4 b1 = ((const float4*)bias)[2 * c8 + 1];
    __half2 q0 = __floats2half2_rn(fmaxf(fmaf(di, lo.x, b0.x), 0.f),
                                   fmaxf(fmaf(di, lo.y, b0.y), 0.f));
    __half2 q1 = __floats2half2_rn(fmaxf(fmaf(di, lo.z, b0.z), 0.f),
                                   fmaxf(fmaf(di, lo.w, b0.w), 0.f));
    __half2 q2 = __floats2half2_rn(fmaxf(fmaf(di, hi.x, b1.x), 0.f),
                                   fmaxf(fmaf(di, hi.y, b1.y), 0.f));
    __half2 q3 = __floats2half2_rn(fmaxf(fmaf(di, hi.z, b1.z), 0.f),
                                   fmaxf(fmaf(di, hi.w, b1.w), 0.f));
    uint4 o;
    o.x = *(unsigned*)&q0; o.y = *(unsigned*)&q1;
    o.z = *(unsigned*)&q2; o.w = *(unsigned*)&q3;
    ((uint4*)out16)[(size_t)i * 16 + c8] = o;
  }
}

// pairs: 4 pairs per wave. uint4 lanes: 16 lanes x 16B = 256B row.
// Subgroups (lane>>4): {A[p+0], B[p+0], A[p+1], B[p+1]} for load0;
// second load covers pairs p+2/p+3 -> 2KB in flight per wave.
// Combine A+B via shfl_down(16); dot with wh2; reduce over 16 lanes.
__global__ __launch_bounds__(256) void k_pairs_h(
    const __half* __restrict__ A, const __half* __restrict__ B,
    const int* __restrict__ pairs, const float* __restrict__ bh1,
    const float* __restrict__ wh2, const float* __restrict__ bh2,
    float* __restrict__ out, int P) {
  int wp = (blockIdx.x * 4 + (threadIdx.x >> 6)) * 4;  // first pair of wave
  int lane = threadIdx.x & 63;
  int sub = lane >> 4;       // 0..3
  int c8 = lane & 15;        // uint4 col within row
  int pr = sub >> 1;         // pair within duo (0/1)
  int ab = sub & 1;          // 0 = A-row, 1 = B-row
  const uint4* T = ab ? (const uint4*)B : (const uint4*)A;
  int pA = wp + pr;          // duo 0
  int pB = wp + 2 + pr;      // duo 1
  uint4 u0 = make_uint4(0, 0, 0, 0), u1 = u0;
  if (pA < P) {
    int r = pairs[2 * pA + ab];
    u0 = T[(size_t)r * 16 + c8];
  }
  if (pB < P) {
    int r = pairs[2 * pB + ab];
    u1 = T[(size_t)r * 16 + c8];
  }
  float4 b0 = ((const float4*)bh1)[2 * c8];
  float4 b1 = ((const float4*)bh1)[2 * c8 + 1];
  float4 w0 = ((const float4*)wh2)[2 * c8];
  float4 w1 = ((const float4*)wh2)[2 * c8 + 1];
  float s0, s1;
  {
    float4 lo = make_float4(0, 0, 0, 0), hi = lo;
    acc8(u0, lo, hi);
    lo.x += __shfl_down(lo.x, 16, 64); lo.y += __shfl_down(lo.y, 16, 64);
    lo.z += __shfl_down(lo.z, 16, 64); lo.w += __shfl_down(lo.w, 16, 64);
    hi.x += __shfl_down(hi.x, 16, 64); hi.y += __shfl_down(hi.y, 16, 64);
    hi.z += __shfl_down(hi.z, 16, 64); hi.w += __shfl_down(hi.w, 16, 64);
    s0 = fmaxf(lo.x + b0.x, 0.f) * w0.x + fmaxf(lo.y + b0.y, 0.f) * w0.y +
         fmaxf(lo.z + b0.z, 0.f) * w0.z + fmaxf(lo.w + b0.w, 0.f) * w0.w +
         fmaxf(hi.x + b1.x, 0.f) * w1.x + fmaxf(hi.y + b1.y, 0.f) * w1.y +
         fmaxf(hi.z + b1.z, 0.f) * w1.z + fmaxf(hi.w + b1.w, 0.f) * w1.w;
  }
  {
    float4 lo = make_float4(0, 0, 0, 0), hi = lo;
    acc8(u1, lo, hi);
    lo.x += __shfl_down(lo.x, 16, 64); lo.y += __shfl_down(lo.y, 16, 64);
    lo.z += __shfl_down(lo.z, 16, 64); lo.w += __shfl_down(lo.w, 16, 64);
    hi.x += __shfl_down(hi.x, 16, 64); hi.y += __shfl_down(hi.y, 16, 64);
    hi.z += __shfl_down(hi.z, 16, 64); hi.w += __shfl_down(hi.w, 16, 64);
    s1 = fmaxf(lo.x + b0.x, 0.f) * w0.x + fmaxf(lo.y + b0.y, 0.f) * w0.y +
         fmaxf(lo.z + b0.z, 0.f) * w0.z + fmaxf(lo.w + b0.w, 0.f) * w0.w +
         fmaxf(hi.x + b1.x, 0.f) * w1.x + fmaxf(hi.y + b1.y, 0.f) * w1.y +
         fmaxf(hi.z + b1.z, 0.f) * w1.z + fmaxf(hi.w + b1.w, 0.f) * w1.w;
  }
  // reduce within each 16-lane group (valid partials live in sub0/sub2)
#pragma unroll
  for (int o = 8; o > 0; o >>= 1) {
    s0 += __shfl_down(s0, o, 64);
    s1 += __shfl_down(s1, o, 64);
  }
  float bb = bh2[0];
  if (lane == 0 && wp < P) out[wp] = s0 + bb;            // pair wp (duo0, A-group lanes 0..15)
  if (lane == 32 && wp + 1 < P) out[wp + 1] = s0 + bb;   // pair wp+1 (lanes 32..47)
  if (lane == 0 && wp + 2 < P) out[wp + 2] = s1 + bb;
  if (lane == 32 && wp + 3 < P) out[wp + 3] = s1 + bb;
}

extern "C" void kernel_launch(void* const* d_in, const int* in_sizes, int n_in,
                              void* d_out, int out_size, void* d_ws, size_t ws_size,
                              hipStream_t stream) {
  const float* x   = (const float*)d_in[0];
  const int* ei    = (const int*)d_in[1];
  const int* pairs = (const int*)d_in[2];
  const float* W1  = (const float*)d_in[3];
  const float* b1  = (const float*)d_in[4];
  const float* W2  = (const float*)d_in[5];
  const float* b2  = (const float*)d_in[6];
  const float* Wh1 = (const float*)d_in[7];
  const float* bh1 = (const float*)d_in[8];
  const float* Wh2 = (const float*)d_in[9];
  const float* bh2 = (const float*)d_in[10];
  (void)n_in; (void)out_size; (void)ws_size;

  int N = in_sizes[0] / 128;
  int E = in_sizes[1] / 2;
  int P = in_sizes[2] / 2;
  const int* src = ei;
  const int* dst = ei + E;
  int KB = (N + BSZ - 1) >> BSH;  // buckets (98 for N=50000)

  char* wsp = (char*)d_ws;
  size_t off = 0;
  auto alloc = [&](size_t bytes) -> void* {
    void* p = wsp + off;
    off += (bytes + 255) & ~(size_t)255;
    return p;
  };
  __half* g16 = (__half*)alloc((size_t)N * 128 * 2);  // messages; reused as A16
  __half* h1  = (__half*)alloc((size_t)N * 128 * 2);  // fp16; reused as B16
  __half* h2  = (__half*)alloc((size_t)N * 128 * 2);  // fp16
  float* dinv = (float*)alloc((size_t)N * 4);
  int* rowptr = (int*)alloc((size_t)(N + 1) * 4);
  unsigned short* colarr = (unsigned short*)alloc((size_t)E * 2);
  int* tmp    = (int*)alloc((size_t)E * 4);
  short* fragH = (short*)alloc(4 * 2048 * 8 * 2);     // 128KB
  short* fragL = (short*)alloc(4 * 2048 * 8 * 2);     // 128KB
  int* gcnt  = (int*)alloc((size_t)(KB + 1) * 4);
  int* gcur  = (int*)alloc((size_t)(KB + 1) * 4);
  __half* A16 = g16;            // g16 dead by the time head runs
  __half* B16 = h1;             // h1 dead after conv2 gemm
  short* fH_W1 = fragH + 0 * 16384;  short* fL_W1 = fragL + 0 * 16384;
  short* fH_W2 = fragH + 1 * 16384;  short* fL_W2 = fragL + 1 * 16384;
  short* fH_Wa = fragH + 2 * 16384;  short* fL_Wa = fragL + 2 * 16384;
  short* fH_Wb = fragH + 3 * 16384;  short* fL_Wb = fragL + 3 * 16384;

  int GB = (N + 63) / 64;          // fp32 gemm: 64 rows per block
  int GF = (N / 16 + 3) / 4;       // f16 gemm: 16 rows/wave, 4 waves/block
  int AB = (N + 3) / 4;            // agg: 4 rows per block

  // zero bucket counters, then fused prep+hist
  hipMemsetAsync(gcnt, 0, (size_t)(KB + 1) * 4, stream);
  hipMemsetAsync(gcur, 0, (size_t)(KB + 1) * 4, stream);
  k_prep_hist<<<32 + HB, 256, 0, stream>>>(W1, W2, Wh1, fragH, fragL,
                                           dst, gcnt, E, KB);
  // CSR build
  k_multisplit<<<(E + MSB - 1) / MSB, 256, 0, stream>>>(src, dst, gcnt, gcur,
                                                        tmp, E, KB);
  k_bucket_build<<<KB, 512, 0, stream>>>(tmp, gcnt, rowptr, dinv, colarr, N, KB, E);
  // conv1 (gemm pre-scales with dinv -> clean agg loops)
  k_gemm_mfma<<<GB, 256, 0, stream>>>(x, fH_W1, fL_W1, dinv, g16, N);
  k_agg_h<<<AB, 256, 0, stream>>>((const __half2*)g16, dinv, rowptr, colarr, b1, h1, N);
  // conv2 (f16 path)
  k_gemm_f16<<<GF, 256, 0, stream>>>(h1, fH_W2, fL_W2, dinv, g16, N);
  k_agg_h<<<AB, 256, 0, stream>>>((const __half2*)g16, dinv, rowptr, colarr, b2, h2, N);
  // head
  k_gemm_dual_f16<<<GF, 256, 0, stream>>>(h2, fH_Wa, fL_Wa, fH_Wb, fL_Wb,
                                          A16, B16, N);
  k_pairs_h<<<(P + 15) / 16, 256, 0, stream>>>(A16, B16, pairs, bh1, Wh2, bh2,
                                               (float*)d_out, P);
}

// Round 17
// 349.202 us; speedup vs baseline: 1.3950x; 1.0114x over previous
//
#include <hip/hip_runtime.h>
#include <hip/hip_fp16.h>

// ---------------------------------------------------------------------------
// LinkPredictionGNN: 2x GCNConv (self-loops, sym-norm) + pair MLP head.
//   memset gc -> K1 prep_w UNION hist -> K2 multisplit UNION gemm1(raw)
//   -> K3 bucket_build -> K4 gscale(dinv) -> K5 agg1 -> K6 gemm2_f16
//   -> K7 agg2 -> K8 gemm_dual_f16 -> K9 pairs
//
// R1/R4: random 4B global writes/atomics -> ~10x line-writeback amp.
// R5: CSR build = 2-level bucket sort, zero global random atomics.
// R6/R7/R14 ALL FAILED (L2-locality for the agg gather): slicing in any
//   form regresses. Monolithic agg ~59.5us (~153MB L2-miss @ 2.86TB/s =
//   L3 random-256B ceiling) is the floor. Do not retry.
// R12 FAILED: per-edge dinv[src] in the agg loop broke pipelining. R16's
//   gscale is different: a separate coalesced ROW pass, agg loop untouched.
// R15: pairs widened to uint4 lanes, 4 pairs/wave (2KB in flight).
// R16: multisplit overlapped with gemm1 (union dispatch; gemm1 no longer
//   needs dinv -> raw fp16 g + k_gscale row pass after bucket_build);
//   gcnt/gcur single memset.
// R2: fp16 tables (absmax budget ~8e-4 < 1.5e-3 threshold).
// R3: gemm1 (fp32 input) double-bf16-split MFMA (Ah.Bh+Al.Bh+Ah.Bl).
// ---------------------------------------------------------------------------

#define BSH 9                 // log2 nodes per bucket
#define BSZ (1 << BSH)        // 512 nodes per bucket
#define MSB 4096              // edges per multisplit batch/block
#define XPAD 132              // LDS row stride (floats) for fp32 gemm staging
#define HB 256                // hist blocks in fused K1

typedef __attribute__((ext_vector_type(8))) short bf16x8;
typedef __attribute__((ext_vector_type(8))) _Float16 f16x8;
typedef __attribute__((ext_vector_type(4))) float f32x4;

__device__ __forceinline__ void acc8(uint4 u, float4& lo, float4& hi) {
  float2 f0 = __half22float2(((const __half2*)&u)[0]);
  float2 f1 = __half22float2(((const __half2*)&u)[1]);
  float2 f2 = __half22float2(((const __half2*)&u)[2]);
  float2 f3 = __half22float2(((const __half2*)&u)[3]);
  lo.x += f0.x; lo.y += f0.y; lo.z += f1.x; lo.w += f1.y;
  hi.x += f2.x; hi.y += f2.y; hi.z += f3.x; hi.w += f3.y;
}

// Exact fp32 -> bf16 hi/lo split.
__device__ __forceinline__ void split8(const float* v, bf16x8& hi, bf16x8& lo) {
#pragma unroll
  for (int j = 0; j < 8; ++j) {
    unsigned u = __float_as_uint(v[j]);
    hi[j] = (short)(u >> 16);
    float lf = v[j] - __uint_as_float(u & 0xffff0000u);
    lo[j] = (short)(__float_as_uint(lf) >> 16);
  }
}

// K1: weight fragment prep UNION dst bucket-histogram (gc pre-zeroed).
__global__ __launch_bounds__(256) void k_prep_hist(
    const float* __restrict__ W1, const float* __restrict__ W2,
    const float* __restrict__ Wh1, short* __restrict__ fragH,
    short* __restrict__ fragL,
    const int* __restrict__ dst, int* __restrict__ gcnt, int e, int kb) {
  if (blockIdx.x >= 32) {
    __shared__ int h4[512];
    int bid = blockIdx.x - 32;
    int tid = threadIdx.x, wid = tid >> 6;
    for (int t = tid; t < 512; t += 256) h4[t] = 0;
    __syncthreads();
    for (int i = bid * 256 + tid; i < e; i += HB * 256) {
      int d = __builtin_nontemporal_load(&dst[i]);
      atomicAdd(&h4[wid * 128 + (d >> BSH)], 1);
    }
    __syncthreads();
    if (tid < kb)
      atomicAdd(&gcnt[tid], h4[tid] + h4[128 + tid] + h4[256 + tid] + h4[384 + tid]);
    return;
  }
  int g = blockIdx.x * 256 + threadIdx.x;
  int w = g >> 11;
  int rem = g & 2047;
  int lane = rem & 63;
  int ts = rem >> 6;
  int t = ts >> 2, s = ts & 3;
  int n = (t << 4) + (lane & 15);
  int k0 = s * 32 + (lane >> 4) * 8;
  const float* W = (w == 0) ? W1 : (w == 1) ? W2 : (w == 2) ? Wh1 : (Wh1 + 128 * 128);
  short h[8], l[8];
#pragma unroll
  for (int j = 0; j < 8; ++j) {
    float x = W[(k0 + j) * 128 + n];
    if (w == 0) {
      unsigned u = __float_as_uint(x);
      h[j] = (short)(u >> 16);
      float lf = x - __uint_as_float(u & 0xffff0000u);
      l[j] = (short)(__float_as_uint(lf) >> 16);
    } else {
      __half hh = __float2half(x);
      h[j] = __half_as_short(hh);
      l[j] = __half_as_short(__float2half(x - __half2float(hh)));
    }
  }
  ((int4*)fragH)[g] = *(int4*)h;
  ((int4*)fragL)[g] = *(int4*)l;
}

// fp32-input gemm body, NO rowscale (raw fp16 out); sX = 64*XPAD floats LDS.
__device__ __forceinline__ void gemm1_body(
    const float* __restrict__ X, const short* __restrict__ fragH,
    const short* __restrict__ fragL, __half* __restrict__ C16, int n,
    int bid, float* sX) {
  int tid = threadIdx.x;
  int row0 = bid * 64;
  const float2* X2 = (const float2*)(X + (size_t)row0 * 128);
#pragma unroll
  for (int it = 0; it < 16; ++it) {
    int t = it * 256 + tid;
    int r = t >> 6, c2 = t & 63;
    int gr = row0 + r;
    float2 v = (gr < n) ? X2[t] : make_float2(0.f, 0.f);
    *(float2*)&sX[r * XPAD + c2 * 2] = v;
  }
  __syncthreads();
  int wid = tid >> 6, lane = tid & 63;
  int r0 = row0 + wid * 16;
  if (r0 >= n) return;
  int m = lane & 15, quad = lane >> 4;
  const float* xrow = sX + (wid * 16 + m) * XPAD;
  f32x4 acc[8];
#pragma unroll
  for (int t = 0; t < 8; ++t) acc[t] = (f32x4)(0.f);
  const int4* FH = (const int4*)fragH;
  const int4* FL = (const int4*)fragL;
#pragma unroll
  for (int s = 0; s < 4; ++s) {
    int k0 = s * 32 + quad * 8;
    float xv[8];
    *(float2*)&xv[0] = *(const float2*)(xrow + k0);
    *(float2*)&xv[2] = *(const float2*)(xrow + k0 + 2);
    *(float2*)&xv[4] = *(const float2*)(xrow + k0 + 4);
    *(float2*)&xv[6] = *(const float2*)(xrow + k0 + 6);
    bf16x8 ah, al;
    split8(xv, ah, al);
#pragma unroll
    for (int t = 0; t < 8; ++t) {
      int idx = (t * 4 + s) * 64 + lane;
      bf16x8 bh = *(const bf16x8*)&FH[idx];
      bf16x8 bl = *(const bf16x8*)&FL[idx];
      acc[t] = __builtin_amdgcn_mfma_f32_16x16x32_bf16(ah, bh, acc[t], 0, 0, 0);
      acc[t] = __builtin_amdgcn_mfma_f32_16x16x32_bf16(al, bh, acc[t], 0, 0, 0);
      acc[t] = __builtin_amdgcn_mfma_f32_16x16x32_bf16(ah, bl, acc[t], 0, 0, 0);
    }
  }
  // C/D layout: col = lane&15, row = quad*4 + reg   [m89-verified]
#pragma unroll
  for (int t = 0; t < 8; ++t) {
#pragma unroll
    for (int r = 0; r < 4; ++r) {
      int row = r0 + quad * 4 + r;
      C16[(size_t)row * 128 + t * 16 + m] = __float2half(acc[t][r]);
    }
  }
}

// multisplit body: per-wave replicated LDS hist; in-block scan of gcnt; one
// global atomic per bucket per batch. packed = (d_local<<16)|src [src<65536]
// lds = at least 4*128 + 4*128 + 128 + 2 ints.
__device__ __forceinline__ void multisplit_body(
    const int* __restrict__ src, const int* __restrict__ dst,
    const int* __restrict__ gcnt, int* __restrict__ gcur,
    int* __restrict__ tmp, int e, int kb, int bid, int* lds) {
  int* h4 = lds;            // 512
  int* off = lds + 512;     // 512
  int* sbase = lds + 1024;  // 128
  int* ws = lds + 1152;     // 2
  int tid = threadIdx.x, wid = tid >> 6, lane = tid & 63;
  for (int t = tid; t < 512; t += 256) h4[t] = 0;
  __syncthreads();
  int i0 = bid * MSB + tid;
  int d[16], rk[16];
#pragma unroll
  for (int u = 0; u < 16; ++u) {
    int i = i0 + u * 256;
    if (i < e) {
      d[u] = __builtin_nontemporal_load(&dst[i]);
      rk[u] = atomicAdd(&h4[wid * 128 + (d[u] >> BSH)], 1);
    }
  }
  __syncthreads();
  int tot = 0;
  if (tid < 128) {
    int c0 = h4[tid], c1 = h4[128 + tid], c2 = h4[256 + tid], c3 = h4[384 + tid];
    off[tid] = 0; off[128 + tid] = c0;
    off[256 + tid] = c0 + c1; off[384 + tid] = c0 + c1 + c2;
    tot = c0 + c1 + c2 + c3;
  }
  int v = (tid < 128 && tid < kb) ? gcnt[tid] : 0;
  int orig = v;
#pragma unroll
  for (int o = 1; o < 64; o <<= 1) {
    int u = __shfl_up(v, o, 64);
    if (lane >= o) v += u;
  }
  if (lane == 63 && wid < 2) ws[wid] = v;
  __syncthreads();
  if (tid < 128) sbase[tid] = ((wid == 1) ? ws[0] : 0) + v - orig;
  __syncthreads();
  if (tid < kb && tot > 0) sbase[tid] += atomicAdd(&gcur[tid], tot);
  __syncthreads();
#pragma unroll
  for (int u = 0; u < 16; ++u) {
    int i = i0 + u * 256;
    if (i < e) {
      int s = __builtin_nontemporal_load(&src[i]);
      int k = d[u] >> BSH;
      tmp[sbase[k] + off[wid * 128 + k] + rk[u]] = ((d[u] & (BSZ - 1)) << 16) | s;
    }
  }
}

// K2: multisplit UNION gemm1 (both independent: ms needs gcnt/gcur from K1/
// memset; gemm1 needs only W1 frags + x). Overlaps CSR edge pass with GEMM.
__global__ __launch_bounds__(256) void k_ms_gemm1(
    const int* __restrict__ src, const int* __restrict__ dst,
    const int* __restrict__ gcnt, int* __restrict__ gcur,
    int* __restrict__ tmp, int e, int kb, int msblocks,
    const float* __restrict__ X, const short* __restrict__ fragH,
    const short* __restrict__ fragL, __half* __restrict__ C16, int n) {
  __shared__ float sX[64 * XPAD];
  if ((int)blockIdx.x < msblocks) {
    multisplit_body(src, dst, gcnt, gcur, tmp, e, kb, blockIdx.x, (int*)sX);
    return;
  }
  gemm1_body(X, fragH, fragL, C16, n, blockIdx.x - msblocks, sX);
}

// one block per bucket: in-block scan of gcnt; per-node degree + scan +
// cursor scatter in LDS. colarr u16, bucket-local (no write-amp).
__global__ __launch_bounds__(512) void k_bucket_build(
    const int* __restrict__ tmp, const int* __restrict__ gcnt,
    int* __restrict__ rowptr, float* __restrict__ dinv,
    unsigned short* __restrict__ colarr, int n, int kb, int e) {
  __shared__ int dl[BSZ], cl[BSZ], sbase[128], ws[8];
  int t = threadIdx.x, b = blockIdx.x;
  int lane = t & 63, w = t >> 6;
  int v = (t < 128 && t < kb) ? gcnt[t] : 0;
  int orig0 = v;
#pragma unroll
  for (int o = 1; o < 64; o <<= 1) {
    int u = __shfl_up(v, o, 64);
    if (lane >= o) v += u;
  }
  if (lane == 63 && w < 2) ws[w] = v;
  dl[t] = 0;
  __syncthreads();
  if (t < 128) sbase[t] = ((w == 1) ? ws[0] : 0) + v - orig0;
  __syncthreads();
  int s0 = sbase[b];
  int s1 = s0 + gcnt[b];
  for (int j = s0 + t; j < s1; j += 512)
    atomicAdd(&dl[((unsigned)tmp[j]) >> 16], 1);
  __syncthreads();
  int dv = dl[t], orig = dv;
#pragma unroll
  for (int o = 1; o < 64; o <<= 1) {
    int u = __shfl_up(dv, o, 64);
    if (lane >= o) dv += u;
  }
  if (lane == 63) ws[w] = dv;
  __syncthreads();
  if (t == 0) {
    int a = 0;
#pragma unroll
    for (int k = 0; k < 8; ++k) { int x = ws[k]; ws[k] = a; a += x; }
  }
  __syncthreads();
  int ex = ws[w] + dv - orig;
  cl[t] = ex;
  int node = (b << BSH) + t;
  if (node < n) {
    rowptr[node] = s0 + ex;
    dinv[node] = rsqrtf((float)(orig + 1));  // +1 self loop
  }
  if (b == kb - 1 && t == 0) rowptr[n] = e;
  __syncthreads();
  for (int j = s0 + t; j < s1; j += 512) {
    int p = tmp[j];
    int r = atomicAdd(&cl[((unsigned)p) >> 16], 1);
    colarr[s0 + r] = (unsigned short)(p & 0xFFFF);
  }
}

// K4: g16[i,:] *= dinv[i] (row pass, coalesced; one uint4 per thread).
__global__ __launch_bounds__(256) void k_gscale(__half* __restrict__ g16,
                                                const float* __restrict__ dinv,
                                                int n) {
  int idx = blockIdx.x * 256 + threadIdx.x;  // uint4 index
  if (idx >= n * 16) return;
  float di = dinv[idx >> 4];
  uint4 u = ((const uint4*)g16)[idx];
  __half2* hp = (__half2*)&u;
#pragma unroll
  for (int k = 0; k < 4; ++k) {
    float2 f = __half22float2(hp[k]);
    hp[k] = __floats2half2_rn(f.x * di, f.y * di);
  }
  ((uint4*)g16)[idx] = u;
}

// f16-input GEMM: C16 = fp16(rowscale * X16 @ W), A fp16-exact, B f16 hi+lo.
__global__ __launch_bounds__(256) void k_gemm_f16(
    const __half* __restrict__ X16, const short* __restrict__ fragH,
    const short* __restrict__ fragL, const float* __restrict__ rowscale,
    __half* __restrict__ C16, int n) {
  int wid = threadIdx.x >> 6, lane = threadIdx.x & 63;
  int r0 = (blockIdx.x * 4 + wid) * 16;
  if (r0 >= n) return;
  int m = lane & 15, quad = lane >> 4;
  const uint4* Xr = (const uint4*)(X16 + (size_t)(r0 + m) * 128);
  f32x4 acc[8];
#pragma unroll
  for (int t = 0; t < 8; ++t) acc[t] = (f32x4)(0.f);
  const int4* FH = (const int4*)fragH;
  const int4* FL = (const int4*)fragL;
#pragma unroll
  for (int s = 0; s < 4; ++s) {
    uint4 av = Xr[quad + 4 * s];
    f16x8 a = *(const f16x8*)&av;
#pragma unroll
    for (int t = 0; t < 8; ++t) {
      int idx = (t * 4 + s) * 64 + lane;
      int4 bhv = FH[idx], blv = FL[idx];
      f16x8 bh = *(const f16x8*)&bhv;
      f16x8 bl = *(const f16x8*)&blv;
      acc[t] = __builtin_amdgcn_mfma_f32_16x16x32_f16(a, bh, acc[t], 0, 0, 0);
      acc[t] = __builtin_amdgcn_mfma_f32_16x16x32_f16(a, bl, acc[t], 0, 0, 0);
    }
  }
  float sc[4];
#pragma unroll
  for (int r = 0; r < 4; ++r)
    sc[r] = rowscale ? rowscale[r0 + quad * 4 + r] : 1.f;
#pragma unroll
  for (int t = 0; t < 8; ++t) {
#pragma unroll
    for (int r = 0; r < 4; ++r) {
      int row = r0 + quad * 4 + r;
      C16[(size_t)row * 128 + t * 16 + m] = __float2half(acc[t][r] * sc[r]);
    }
  }
}

// Dual-output f16 GEMM for the head (reads X16 once; no rowscale).
__global__ __launch_bounds__(256) void k_gemm_dual_f16(
    const __half* __restrict__ X16,
    const short* __restrict__ fHa, const short* __restrict__ fLa,
    const short* __restrict__ fHb, const short* __restrict__ fLb,
    __half* __restrict__ A16, __half* __restrict__ B16, int n) {
  int wid = threadIdx.x >> 6, lane = threadIdx.x & 63;
  int r0 = (blockIdx.x * 4 + wid) * 16;
  if (r0 >= n) return;
  int m = lane & 15, quad = lane >> 4;
  const uint4* Xr = (const uint4*)(X16 + (size_t)(r0 + m) * 128);
  f32x4 accA[8], accB[8];
#pragma unroll
  for (int t = 0; t < 8; ++t) { accA[t] = (f32x4)(0.f); accB[t] = (f32x4)(0.f); }
  const int4* FHa = (const int4*)fHa; const int4* FLa = (const int4*)fLa;
  const int4* FHb = (const int4*)fHb; const int4* FLb = (const int4*)fLb;
#pragma unroll
  for (int s = 0; s < 4; ++s) {
    uint4 av = Xr[quad + 4 * s];
    f16x8 a = *(const f16x8*)&av;
#pragma unroll
    for (int t = 0; t < 8; ++t) {
      int idx = (t * 4 + s) * 64 + lane;
      int4 v0 = FHa[idx], v1 = FLa[idx], v2 = FHb[idx], v3 = FLb[idx];
      accA[t] = __builtin_amdgcn_mfma_f32_16x16x32_f16(a, *(const f16x8*)&v0, accA[t], 0, 0, 0);
      accA[t] = __builtin_amdgcn_mfma_f32_16x16x32_f16(a, *(const f16x8*)&v1, accA[t], 0, 0, 0);
      accB[t] = __builtin_amdgcn_mfma_f32_16x16x32_f16(a, *(const f16x8*)&v2, accB[t], 0, 0, 0);
      accB[t] = __builtin_amdgcn_mfma_f32_16x16x32_f16(a, *(const f16x8*)&v3, accB[t], 0, 0, 0);
    }
  }
#pragma unroll
  for (int t = 0; t < 8; ++t) {
#pragma unroll
    for (int r = 0; r < 4; ++r) {
      int row = r0 + quad * 4 + r;
      A16[(size_t)row * 128 + t * 16 + m] = __float2half(accA[t][r]);
      B16[(size_t)row * 128 + t * 16 + m] = __float2half(accB[t][r]);
    }
  }
}

// out16[i,:] = fp16(relu(dinv[i] * (g[i,:] + sum g[col[e],:]) + bias))
// R13 known-good monolithic gather: uint4 lanes, 4 edge subgroups, 4-deep
// unroll = 16 edges in flight. DO NOT slice (R6/R7/R14 all regressed).
__global__ __launch_bounds__(256) void k_agg_h(
    const __half2* __restrict__ g2, const float* __restrict__ dinv,
    const int* __restrict__ rowptr, const unsigned short* __restrict__ col,
    const float* __restrict__ bias, __half* __restrict__ out16, int n) {
  int i = blockIdx.x * 4 + (threadIdx.x >> 6);
  if (i >= n) return;
  int lane = threadIdx.x & 63;
  int sub = lane >> 4;
  int c8 = lane & 15;
  const uint4* G = (const uint4*)g2;
  float4 z = make_float4(0.f, 0.f, 0.f, 0.f);
  float4 lo0 = z, lo1 = z, lo2 = z, lo3 = z, hi0 = z, hi1 = z, hi2 = z, hi3 = z;
  if (sub == 0) acc8(G[(size_t)i * 16 + c8], lo0, hi0);  // self loop once
  int beg = rowptr[i], end = rowptr[i + 1];
  int j = beg;
  for (; j + 16 <= end; j += 16) {
    int s0 = __builtin_nontemporal_load(&col[j + sub]);
    int s1 = __builtin_nontemporal_load(&col[j + 4 + sub]);
    int s2 = __builtin_nontemporal_load(&col[j + 8 + sub]);
    int s3 = __builtin_nontemporal_load(&col[j + 12 + sub]);
    uint4 u0 = G[(size_t)s0 * 16 + c8];
    uint4 u1 = G[(size_t)s1 * 16 + c8];
    uint4 u2 = G[(size_t)s2 * 16 + c8];
    uint4 u3 = G[(size_t)s3 * 16 + c8];
    acc8(u0, lo0, hi0); acc8(u1, lo1, hi1);
    acc8(u2, lo2, hi2); acc8(u3, lo3, hi3);
  }
  for (; j + 4 <= end; j += 4) {
    int s0 = __builtin_nontemporal_load(&col[j + sub]);
    acc8(G[(size_t)s0 * 16 + c8], lo1, hi1);
  }
  int rem = end - j;
  if (sub < rem) {
    int s0 = __builtin_nontemporal_load(&col[j + sub]);
    acc8(G[(size_t)s0 * 16 + c8], lo2, hi2);
  }
  float4 lo, hi;
  lo.x = (lo0.x + lo1.x) + (lo2.x + lo3.x);
  lo.y = (lo0.y + lo1.y) + (lo2.y + lo3.y);
  lo.z = (lo0.z + lo1.z) + (lo2.z + lo3.z);
  lo.w = (lo0.w + lo1.w) + (lo2.w + lo3.w);
  hi.x = (hi0.x + hi1.x) + (hi2.x + hi3.x);
  hi.y = (hi0.y + hi1.y) + (hi2.y + hi3.y);
  hi.z = (hi0.z + hi1.z) + (hi2.z + hi3.z);
  hi.w = (hi0.w + hi1.w) + (hi2.w + hi3.w);
  lo.x += __shfl_down(lo.x, 32, 64); lo.x += __shfl_down(lo.x, 16, 64);
  lo.y += __shfl_down(lo.y, 32, 64); lo.y += __shfl_down(lo.y, 16, 64);
  lo.z += __shfl_down(lo.z, 32, 64); lo.z += __shfl_down(lo.z, 16, 64);
  lo.w += __shfl_down(lo.w, 32, 64); lo.w += __shfl_down(lo.w, 16, 64);
  hi.x += __shfl_down(hi.x, 32, 64); hi.x += __shfl_down(hi.x, 16, 64);
  hi.y += __shfl_down(hi.y, 32, 64); hi.y += __shfl_down(hi.y, 16, 64);
  hi.z += __shfl_down(hi.z, 32, 64); hi.z += __shfl_down(hi.z, 16, 64);
  hi.w += __shfl_down(hi.w, 32, 64); hi.w += __shfl_down(hi.w, 16, 64);
  if (sub == 0) {
    float di = dinv[i];
    float4 b0 = ((const float4*)bias)[2 * c8];
    float4 b1 = ((const float4*)bias)[2 * c8 + 1];
    __half2 q0 = __floats2half2_rn(fmaxf(fmaf(di, lo.x, b0.x), 0.f),
                                   fmaxf(fmaf(di, lo.y, b0.y), 0.f));
    __half2 q1 = __floats2half2_rn(fmaxf(fmaf(di, lo.z, b0.z), 0.f),
                                   fmaxf(fmaf(di, lo.w, b0.w), 0.f));
    __half2 q2 = __floats2half2_rn(fmaxf(fmaf(di, hi.x, b1.x), 0.f),
                                   fmaxf(fmaf(di, hi.y, b1.y), 0.f));
    __half2 q3 = __floats2half2_rn(fmaxf(fmaf(di, hi.z, b1.z), 0.f),
                                   fmaxf(fmaf(di, hi.w, b1.w), 0.f));
    uint4 o;
    o.x = *(unsigned*)&q0; o.y = *(unsigned*)&q1;
    o.z = *(unsigned*)&q2; o.w = *(unsigned*)&q3;
    ((uint4*)out16)[(size_t)i * 16 + c8] = o;
  }
}

// pairs: 4 pairs per wave (R15). uint4 lanes: 16 lanes x 16B = 256B row.
__global__ __launch_bounds__(256) void k_pairs_h(
    const __half* __restrict__ A, const __half* __restrict__ B,
    const int* __restrict__ pairs, const float* __restrict__ bh1,
    const float* __restrict__ wh2, const float* __restrict__ bh2,
    float* __restrict__ out, int P) {
  int wp = (blockIdx.x * 4 + (threadIdx.x >> 6)) * 4;
  int lane = threadIdx.x & 63;
  int sub = lane >> 4;
  int c8 = lane & 15;
  int pr = sub >> 1;
  int ab = sub & 1;
  const uint4* T = ab ? (const uint4*)B : (const uint4*)A;
  int pA = wp + pr;
  int pB = wp + 2 + pr;
  uint4 u0 = make_uint4(0, 0, 0, 0), u1 = u0;
  if (pA < P) {
    int r = pairs[2 * pA + ab];
    u0 = T[(size_t)r * 16 + c8];
  }
  if (pB < P) {
    int r = pairs[2 * pB + ab];
    u1 = T[(size_t)r * 16 + c8];
  }
  float4 b0 = ((const float4*)bh1)[2 * c8];
  float4 b1 = ((const float4*)bh1)[2 * c8 + 1];
  float4 w0 = ((const float4*)wh2)[2 * c8];
  float4 w1 = ((const float4*)wh2)[2 * c8 + 1];
  float s0, s1;
  {
    float4 lo = make_float4(0, 0, 0, 0), hi = lo;
    acc8(u0, lo, hi);
    lo.x += __shfl_down(lo.x, 16, 64); lo.y += __shfl_down(lo.y, 16, 64);
    lo.z += __shfl_down(lo.z, 16, 64); lo.w += __shfl_down(lo.w, 16, 64);
    hi.x += __shfl_down(hi.x, 16, 64); hi.y += __shfl_down(hi.y, 16, 64);
    hi.z += __shfl_down(hi.z, 16, 64); hi.w += __shfl_down(hi.w, 16, 64);
    s0 = fmaxf(lo.x + b0.x, 0.f) * w0.x + fmaxf(lo.y + b0.y, 0.f) * w0.y +
         fmaxf(lo.z + b0.z, 0.f) * w0.z + fmaxf(lo.w + b0.w, 0.f) * w0.w +
         fmaxf(hi.x + b1.x, 0.f) * w1.x + fmaxf(hi.y + b1.y, 0.f) * w1.y +
         fmaxf(hi.z + b1.z, 0.f) * w1.z + fmaxf(hi.w + b1.w, 0.f) * w1.w;
  }
  {
    float4 lo = make_float4(0, 0, 0, 0), hi = lo;
    acc8(u1, lo, hi);
    lo.x += __shfl_down(lo.x, 16, 64); lo.y += __shfl_down(lo.y, 16, 64);
    lo.z += __shfl_down(lo.z, 16, 64); lo.w += __shfl_down(lo.w, 16, 64);
    hi.x += __shfl_down(hi.x, 16, 64); hi.y += __shfl_down(hi.y, 16, 64);
    hi.z += __shfl_down(hi.z, 16, 64); hi.w += __shfl_down(hi.w, 16, 64);
    s1 = fmaxf(lo.x + b0.x, 0.f) * w0.x + fmaxf(lo.y + b0.y, 0.f) * w0.y +
         fmaxf(lo.z + b0.z, 0.f) * w0.z + fmaxf(lo.w + b0.w, 0.f) * w0.w +
         fmaxf(hi.x + b1.x, 0.f) * w1.x + fmaxf(hi.y + b1.y, 0.f) * w1.y +
         fmaxf(hi.z + b1.z, 0.f) * w1.z + fmaxf(hi.w + b1.w, 0.f) * w1.w;
  }
#pragma unroll
  for (int o = 8; o > 0; o >>= 1) {
    s0 += __shfl_down(s0, o, 64);
    s1 += __shfl_down(s1, o, 64);
  }
  float bb = bh2[0];
  if (lane == 0 && wp < P) out[wp] = s0 + bb;
  if (lane == 32 && wp + 1 < P) out[wp + 1] = s0 + bb;
  if (lane == 0 && wp + 2 < P) out[wp + 2] = s1 + bb;
  if (lane == 32 && wp + 3 < P) out[wp + 3] = s1 + bb;
}

extern "C" void kernel_launch(void* const* d_in, const int* in_sizes, int n_in,
                              void* d_out, int out_size, void* d_ws, size_t ws_size,
                              hipStream_t stream) {
  const float* x   = (const float*)d_in[0];
  const int* ei    = (const int*)d_in[1];
  const int* pairs = (const int*)d_in[2];
  const float* W1  = (const float*)d_in[3];
  const float* b1  = (const float*)d_in[4];
  const float* W2  = (const float*)d_in[5];
  const float* b2  = (const float*)d_in[6];
  const float* Wh1 = (const float*)d_in[7];
  const float* bh1 = (const float*)d_in[8];
  const float* Wh2 = (const float*)d_in[9];
  const float* bh2 = (const float*)d_in[10];
  (void)n_in; (void)out_size; (void)ws_size;

  int N = in_sizes[0] / 128;
  int E = in_sizes[1] / 2;
  int P = in_sizes[2] / 2;
  const int* src = ei;
  const int* dst = ei + E;
  int KB = (N + BSZ - 1) >> BSH;  // buckets (98 for N=50000)

  char* wsp = (char*)d_ws;
  size_t off = 0;
  auto alloc = [&](size_t bytes) -> void* {
    void* p = wsp + off;
    off += (bytes + 255) & ~(size_t)255;
    return p;
  };
  __half* g16 = (__half*)alloc((size_t)N * 128 * 2);  // messages; reused as A16
  __half* h1  = (__half*)alloc((size_t)N * 128 * 2);  // fp16; reused as B16
  __half* h2  = (__half*)alloc((size_t)N * 128 * 2);  // fp16
  float* dinv = (float*)alloc((size_t)N * 4);
  int* rowptr = (int*)alloc((size_t)(N + 1) * 4);
  unsigned short* colarr = (unsigned short*)alloc((size_t)E * 2);
  int* tmp    = (int*)alloc((size_t)E * 4);
  short* fragH = (short*)alloc(4 * 2048 * 8 * 2);     // 128KB
  short* fragL = (short*)alloc(4 * 2048 * 8 * 2);     // 128KB
  int* gc     = (int*)alloc(2 * 128 * 4);             // [0:128) gcnt, [128:256) gcur
  int* gcnt = gc;
  int* gcur = gc + 128;
  __half* A16 = g16;            // g16 dead by the time head runs
  __half* B16 = h1;             // h1 dead after conv2 gemm
  short* fH_W1 = fragH + 0 * 16384;  short* fL_W1 = fragL + 0 * 16384;
  short* fH_W2 = fragH + 1 * 16384;  short* fL_W2 = fragL + 1 * 16384;
  short* fH_Wa = fragH + 2 * 16384;  short* fL_Wa = fragL + 2 * 16384;
  short* fH_Wb = fragH + 3 * 16384;  short* fL_Wb = fragL + 3 * 16384;

  int GB = (N + 63) / 64;          // fp32 gemm: 64 rows per block
  int GF = (N / 16 + 3) / 4;       // f16 gemm: 16 rows/wave, 4 waves/block
  int AB = (N + 3) / 4;            // agg: 4 rows per block
  int MS = (E + MSB - 1) / MSB;    // multisplit blocks

  // one memset for both counter arrays, then fused prep+hist
  hipMemsetAsync(gc, 0, 2 * 128 * 4, stream);
  k_prep_hist<<<32 + HB, 256, 0, stream>>>(W1, W2, Wh1, fragH, fragL,
                                           dst, gcnt, E, KB);
  // K2: multisplit UNION gemm1 (raw, unscaled)
  k_ms_gemm1<<<MS + GB, 256, 0, stream>>>(src, dst, gcnt, gcur, tmp, E, KB, MS,
                                          x, fH_W1, fL_W1, g16, N);
  // K3: per-bucket LDS sort -> rowptr/dinv/colarr
  k_bucket_build<<<KB, 512, 0, stream>>>(tmp, gcnt, rowptr, dinv, colarr, N, KB, E);
  // K4: apply dinv row-scale to g16 (coalesced; agg loops stay clean)
  k_gscale<<<(N * 16 + 255) / 256, 256, 0, stream>>>(g16, dinv, N);
  // conv1 agg
  k_agg_h<<<AB, 256, 0, stream>>>((const __half2*)g16, dinv, rowptr, colarr, b1, h1, N);
  // conv2 (f16 path)
  k_gemm_f16<<<GF, 256, 0, stream>>>(h1, fH_W2, fL_W2, dinv, g16, N);
  k_agg_h<<<AB, 256, 0, stream>>>((const __half2*)g16, dinv, rowptr, colarr, b2, h2, N);
  // head
  k_gemm_dual_f16<<<GF, 256, 0, stream>>>(h2, fH_Wa, fL_Wa, fH_Wb, fL_Wb,
                                          A16, B16, N);
  k_pairs_h<<<(P + 15) / 16, 256, 0, stream>>>(A16, B16, pairs, bh1, Wh2, bh2,
                                               (float*)d_out, P);
}